// Round 6
// baseline (12915.831 us; speedup 1.0000x reference)
//
#include <hip/hip_runtime.h>
#include <stdint.h>

// ---------------------------------------------------------------------------
// Fused spiking-MLP forward: 20 timesteps, B=16384, 784 -> 400 -> 10.
//
// RNG: jax threefry, PARTITIONABLE semantics (verified absmax 0.0):
//   key_t = TF((0,42),(0,t)); per element e: bits = x0^x1 of TF(key_t,(0,e));
//   u = bitcast((bits>>9)|0x3f800000)-1.0f; xi = (x > u).
//
// V7 (vs V6 @5078us). V2-V6 plateau at ~5.1-5.3ms across all staging
// variants = fixed per-tile critical path (mask LDS chain + branch bubbles)
// walked in LOCKSTEP by all 16 resident waves (2 blocks/CU, LDS-capped).
// Fix: occupancy + de-phasing, same minimum-issue branchy loop:
//  * 2048 blocks x 512 thr; 8 samples/block; 8 waves = 2 sample-groups x
//    4 neuron-QUARTERS (k=2/thread) -> mem1+acc1 = 32 VGPR, ~75 total.
//  * f32 LDS staging, packed [dt][kq][lane][k] layout: wt = 32KB, total
//    ~35KB -> 3-4 blocks/CU (24-32 waves). Independent blocks at
//    independent phases fill each other's stalls. Consumer: ONE
//    ds_read_b64 + 2 cvt per dt (vs 4 reads).
//  * Epilogue/L2 as V6 (lean, reordered, spill-free).
// Numerics: f64 state, per-stream ascending-d add order -> bit-identical.
// ---------------------------------------------------------------------------

#define BSZ    16384
#define INDIM  784
#define HID    400
#define ODIM   10
#define TSTEPS 20

#define TD   8            // d-tile size
#define NT   98           // 784/8 tiles per sweep
#define WTJ  512          // padded (permuted) neuron slots per dt
#define XIW  26           // xi words per sample
#define SPW  14           // spike words per sample

__device__ __forceinline__ void tfr(uint32_t& x0, uint32_t& x1, int r) {
  x0 += x1;
  x1 = (x1 << r) | (x1 >> (32 - r));
  x1 ^= x0;
}

__device__ __forceinline__ uint2 tf2x32(uint32_t k0, uint32_t k1,
                                        uint32_t c0, uint32_t c1) {
  uint32_t k2 = k0 ^ k1 ^ 0x1BD11BDAu;
  uint32_t x0 = c0 + k0, x1 = c1 + k1;
  tfr(x0,x1,13); tfr(x0,x1,15); tfr(x0,x1,26); tfr(x0,x1,6);
  x0 += k1; x1 += k2 + 1u;
  tfr(x0,x1,17); tfr(x0,x1,29); tfr(x0,x1,16); tfr(x0,x1,24);
  x0 += k2; x1 += k0 + 2u;
  tfr(x0,x1,13); tfr(x0,x1,15); tfr(x0,x1,26); tfr(x0,x1,6);
  x0 += k0; x1 += k1 + 3u;
  tfr(x0,x1,17); tfr(x0,x1,29); tfr(x0,x1,16); tfr(x0,x1,24);
  x0 += k1; x1 += k2 + 4u;
  tfr(x0,x1,13); tfr(x0,x1,15); tfr(x0,x1,26); tfr(x0,x1,6);
  x0 += k2; x1 += k0 + 5u;
  return make_uint2(x0, x1);
}

__device__ __forceinline__ float bits_to_unif(uint32_t b) {
  return __uint_as_float((b >> 9) | 0x3f800000u) - 1.0f;
}

// permuted LDS slot for neuron j: [kq][lane][k] within each dt-plane
__device__ __forceinline__ int permj(int j) {
  return 128 * (j >> 7) + 2 * (j & 63) + ((j >> 6) & 1);
}

__global__ __launch_bounds__(512, 6)
void snn_fused(const float* __restrict__ x,  const float* __restrict__ W1,
               const float* __restrict__ b1, const float* __restrict__ W2,
               const float* __restrict__ b2, float* __restrict__ out) {
  __shared__ float    wt[2][TD * WTJ];     // 32768 B, double-buffered
  __shared__ uint32_t xib[2][8][XIW];      // 1664 B  (xi bits for t0,t1)
  __shared__ uint32_t spk[2][8][SPW];      // 896 B   (spikes for t0,t1)

  const int tid  = threadIdx.x;            // 0..511
  const int g    = blockIdx.x;             // 0..2047
  const int wv   = tid >> 6;               // wave 0..7
  const int sg   = wv >> 2;                // sample group 0..1 (4 samples)
  const int kq   = wv & 3;                 // neuron quarter: j base 128*kq
  const int lane = tid & 63;

  // zero padded slots (those mapping to j >= 400) in BOTH buffers once
  for (int i = tid; i < 2 * TD * WTJ; i += 512) {
    const int pj = i & (WTJ - 1);
    const int j  = 128 * (pj >> 7) + 64 * (pj & 1) + ((pj >> 1) & 63);
    if (j >= HID) (&wt[0][0])[i] = 0.0f;
  }

  // biases of owned neurons j = 128*kq + 64*k + lane (dummies stay 0)
  double bb[2];
#pragma unroll
  for (int k = 0; k < 2; ++k) {
    const int j = 128 * kq + 64 * k + lane;
    bb[k] = (j < HID) ? (double)b1[j] : 0.0;
  }

  // persistent layer-1 state: samples 4sg+s, neurons j = 128kq + 64k + lane
  double   mem1[4][2];
  double   acc1[4][2];
  uint32_t spv[4];
#pragma unroll
  for (int s = 0; s < 4; ++s) {
    spv[s] = 0u;
#pragma unroll
    for (int k = 0; k < 2; ++k) { mem1[s][k] = 0.0; acc1[s][k] = 0.0; }
  }

  // layer-2 ownership: tid<80 -> (sample ls, output lo)
  const int ls = tid / ODIM;
  const int lo = tid - ls * ODIM;
  double m2 = 0.0;
  int    s2 = 0, cnt2 = 0;
  const double b2r = (tid < 80) ? (double)b2[lo] : 0.0;

  // Lean dense layer-2 (V6): one float4 + spike-nibble per iteration,
  // 4 partial f64 dots (f64 reorder safe; fma exact for bit in {0,1}).
  auto layer2_step = [&](int tt) {
    if (tid < 80) {
      double a2 = s2 ? 0.0 : m2 * 0.2;
      double d0 = 0.0, d1 = 0.0, d2 = 0.0, d3 = 0.0;
      const float4* w2p = (const float4*)(W2 + lo * HID);
#pragma unroll 4
      for (int qq = 0; qq < 100; ++qq) {   // j = 4*qq .. 4*qq+3
        const uint32_t nib = (spk[tt][ls][qq >> 3] >> ((qq & 7) * 4)) & 0xFu;
        const float4 v4 = w2p[qq];
        d0 = fma((double)v4.x, (double)(nib & 1u),        d0);
        d1 = fma((double)v4.y, (double)((nib >> 1) & 1u), d1);
        d2 = fma((double)v4.z, (double)((nib >> 2) & 1u), d2);
        d3 = fma((double)v4.w, (double)((nib >> 3) & 1u), d3);
      }
      m2 = (a2 + ((d0 + d1) + (d2 + d3))) + b2r;
      s2 = (m2 > 0.5) ? 1 : 0;
      cnt2 += s2;
    }
  };

  // ---- prime the pipeline: buf0 <- tile 0, regs <- tile 1 ----
  const bool stager = (tid < HID);
  const int  pj     = permj(tid);          // stager's slot within dt-plane
  float4 va = make_float4(0,0,0,0), vb = va;
  if (stager) {
    const float4* s0 = (const float4*)(W1 + tid * INDIM);
    va = s0[0]; vb = s0[1];                // tile 0 (8 floats)
    float* dst = &wt[0][pj];
    dst[0*WTJ] = va.x;  dst[1*WTJ] = va.y;
    dst[2*WTJ] = va.z;  dst[3*WTJ] = va.w;
    dst[4*WTJ] = vb.x;  dst[5*WTJ] = vb.y;
    dst[6*WTJ] = vb.z;  dst[7*WTJ] = vb.w;
    const float4* s1 = (const float4*)(W1 + tid * INDIM + TD);
    va = s1[0]; vb = s1[1];                // tile 1
  }
  int cur = 0;
  int ld  = 2;                             // next tile index to load (mod NT)
  __syncthreads();                         // buf0 + pad zeros visible

  for (int tp = 0; tp < TSTEPS / 2; ++tp) {
    // ---- step keys for the pair ----
    const uint2 ka = tf2x32(0u, 42u, 0u, (uint32_t)(2 * tp));
    const uint2 kb = tf2x32(0u, 42u, 0u, (uint32_t)(2 * tp + 1));
    const uint32_t kx[2] = { ka.x, kb.x };
    const uint32_t ky[2] = { ka.y, kb.y };

    // ---- xi generation for BOTH steps; c-range split across 4 kq waves --
    const int cA = kq * 3 + (kq > 0);      // {0,4,7,10}
    const int cB = cA + 3 + (kq == 0);     // {4,7,10,13}
    for (int s = 0; s < 4; ++s) {
      const int q   = 4 * sg + s;          // block-sample 0..7
      const int row = g * 4 + s + sg * 8192;
      for (int c = cA; c < cB; ++c) {
        const int d = c * 64 + lane;
        const bool valid = (d < INDIM);
        float xv = 0.0f;
        if (valid) xv = x[row * INDIM + d];
        const uint32_t e = (uint32_t)row * (uint32_t)INDIM + (uint32_t)d;
#pragma unroll
        for (int tt = 0; tt < 2; ++tt) {
          int xb = 0;
          if (valid) {
            uint2 r = tf2x32(kx[tt], ky[tt], 0u, e);
            xb = xv > bits_to_unif(r.x ^ r.y);
          }
          unsigned long long m = __ballot(xb);
          if (lane == 0) {
            xib[tt][q][2*c]     = (uint32_t)m;
            xib[tt][q][2*c + 1] = (uint32_t)(m >> 32);
          }
        }
      }
    }
    __syncthreads();                       // xib visible to all waves

    // ---- decay + reset into t0 accumulator; zero t1 accumulator ----
#pragma unroll
    for (int s = 0; s < 4; ++s)
#pragma unroll
      for (int k = 0; k < 2; ++k) {
        mem1[s][k] = ((spv[s] >> k) & 1u) ? 0.0 : mem1[s][k] * 0.2;
        acc1[s][k] = 0.0;
      }

    // ---- ONE sweep over 98 tiles feeds BOTH timesteps (double-buffered) --
    for (int td = 0; td < NT; ++td) {
      // stage tile td+1 into buf^1 (overlaps consume of buf), then
      // prefetch tile 'ld' from global (lands during next consume phase)
      if (stager) {
        float* dst = &wt[cur ^ 1][pj];
        dst[0*WTJ] = va.x;  dst[1*WTJ] = va.y;
        dst[2*WTJ] = va.z;  dst[3*WTJ] = va.w;
        dst[4*WTJ] = vb.x;  dst[5*WTJ] = vb.y;
        dst[6*WTJ] = vb.z;  dst[7*WTJ] = vb.w;
        const float4* src = (const float4*)(W1 + tid * INDIM + ld * TD);
        va = src[0]; vb = src[1];
      }
      ld = (ld + 1 == NT) ? 0 : ld + 1;

      // xi bit-words for this tile, hoisted to SGPR (wave-uniform)
      const int wi = td >> 2, sh = (td & 3) * 8;
      uint32_t bA[4], bB[4];
#pragma unroll
      for (int s = 0; s < 4; ++s) {
        bA[s] = (uint32_t)__builtin_amdgcn_readfirstlane(
                  (int)((xib[0][4*sg + s][wi] >> sh) & 0xFFu));
        bB[s] = (uint32_t)__builtin_amdgcn_readfirstlane(
                  (int)((xib[1][4*sg + s][wi] >> sh) & 0xFFu));
      }

      const float* wp = &wt[cur][kq * 128 + lane * 2];
#pragma unroll
      for (int dt = 0; dt < TD; ++dt) {
        const float2 w2 = *(const float2*)(wp + dt * WTJ); // 1x ds_read_b64
        const double wd0 = (double)w2.x;
        const double wd1 = (double)w2.y;
#pragma unroll
        for (int s = 0; s < 4; ++s) {
          if (bA[s] & (1u << dt)) {        // scalar test: s_and + s_cbranch
            mem1[s][0] += wd0;  mem1[s][1] += wd1;
          }
          if (bB[s] & (1u << dt)) {
            acc1[s][0] += wd0;  acc1[s][1] += wd1;
          }
        }
      }

      __syncthreads();                     // buf consumed; buf^1 ready
      cur ^= 1;
    }

    // ---- finalize t0: + b1, threshold, pack spikes -> spk[0] ----
#pragma unroll
    for (int s = 0; s < 4; ++s) {
      uint32_t m = 0u;
#pragma unroll
      for (int k = 0; k < 2; ++k) {
        mem1[s][k] += bb[k];
        if (mem1[s][k] > 0.5) m |= (1u << k);
      }
      spv[s] = m;
#pragma unroll
      for (int k = 0; k < 2; ++k) {
        unsigned long long bm = __ballot((m >> k) & 1u);
        const int w0 = 4 * kq + 2 * k;
        if (lane == 0 && w0 < SPW) {
          spk[0][4*sg + s][w0]     = (uint32_t)bm;
          spk[0][4*sg + s][w0 + 1] = (uint32_t)(bm >> 32);
        }
      }
    }

    // ---- finalize t1: decay(t0) + acc1 + b1, threshold -> spk[1] ----
    // (acc1 dies here, BEFORE layer2 runs -> no register overlap)
#pragma unroll
    for (int s = 0; s < 4; ++s) {
      uint32_t m = 0u;
#pragma unroll
      for (int k = 0; k < 2; ++k) {
        double v = ((spv[s] >> k) & 1u) ? 0.0 : mem1[s][k] * 0.2;
        v += acc1[s][k];
        v += bb[k];
        mem1[s][k] = v;
        if (v > 0.5) m |= (1u << k);
      }
      spv[s] = m;
#pragma unroll
      for (int k = 0; k < 2; ++k) {
        unsigned long long bm = __ballot((m >> k) & 1u);
        const int w0 = 4 * kq + 2 * k;
        if (lane == 0 && w0 < SPW) {
          spk[1][4*sg + s][w0]     = (uint32_t)bm;
          spk[1][4*sg + s][w0 + 1] = (uint32_t)(bm >> 32);
        }
      }
    }
    __syncthreads();                       // spikes(t0,t1) visible

    layer2_step(0);                        // t0
    layer2_step(1);                        // t1
    // no barrier: layer2 overlaps next pair's xi-gen; next spk write is a
    // full sweep (99 barriers) away.
  }

  // ---- output: h2_sum / 20 ----
  if (tid < 80) {
    const int row = g * 4 + (ls & 3) + ((ls >= 4) ? 8192 : 0);
    out[row * ODIM + lo] = (float)((double)cnt2 / 20.0);
  }
}

extern "C" void kernel_launch(void* const* d_in, const int* in_sizes, int n_in,
                              void* d_out, int out_size, void* d_ws, size_t ws_size,
                              hipStream_t stream) {
  const float* x  = (const float*)d_in[0];
  const float* W1 = (const float*)d_in[1];
  const float* b1 = (const float*)d_in[2];
  const float* W2 = (const float*)d_in[3];
  const float* b2 = (const float*)d_in[4];
  // d_in[5] = time_window (int, ==20) — compile-time constant here.
  float* out = (float*)d_out;
  hipLaunchKernelGGL(snn_fused, dim3(2048), dim3(512), 0, stream,
                     x, W1, b1, W2, b2, out);
}

// Round 7
// 11740.453 us; speedup vs baseline: 1.1001x; 1.1001x over previous
//
#include <hip/hip_runtime.h>
#include <stdint.h>

// ---------------------------------------------------------------------------
// Fused spiking-MLP forward: 20 timesteps, B=16384, 784 -> 400 -> 10.
//
// RNG: jax threefry, PARTITIONABLE semantics (verified absmax 0.0):
//   key_t = TF((0,42),(0,t)); per element e: bits = x0^x1 of TF(key_t,(0,e));
//   u = bitcast((bits>>9)|0x3f800000)-1.0f; xi = (x > u).
//
// V8 (vs V6 @5078us; V7 @12916 failed: 1.9e8 LDS bank conflicts from the
// packed float2 layout + 400MB scratch spill from the 80-reg cap).
// Plateau diagnosis: ~1000 per-tile barriers phase-lock all resident waves
// on a fixed serial segment (mask fetch -> ds_read -> branchy adds ->
// barrier); TLP can't fill bubbles when every wave bubbles together.
// V8 removes the lockstep: NO W1 LDS staging, NO stager waves, NO hot-loop
// barriers. Waves read W1 DIRECTLY from global: lane reads W1[j][d] with
// row stride 3136B; each 64B line covers 16 consecutive d -> per-wave
// working set 256 rows x 64B = 16KB (L1-resident), W1 1.25MB L2-resident.
// Loads batched 16/half-chunk, independent of gates -> latency under adds;
// drifted waves cover each other's branch bubbles. 2 barriers per
// timestep-pair (xi-gen, spike-pack) vs ~101.
//  * 2048 blocks x 256 thr; 4 waves = 2 sample-groups x 2 neuron-halves;
//    8 samples/block; k=4 neurons/thread (f64 state 64 VGPR, cap 128 via
//    launch_bounds(256,4) -> no spill).
//  * Same minimum-issue branchy gated adds; same per-(sample,neuron)
//    ascending-d f64 add order -> bit-identical. Lean layer2 as V6.
// ---------------------------------------------------------------------------

#define BSZ    16384
#define INDIM  784
#define HID    400
#define ODIM   10
#define TSTEPS 20

#define TD   8            // d-chunk per mask byte
#define NT   98           // 784/8 chunks per sweep
#define XIW  26           // xi words per sample
#define SPW  14           // spike words per sample

__device__ __forceinline__ void tfr(uint32_t& x0, uint32_t& x1, int r) {
  x0 += x1;
  x1 = (x1 << r) | (x1 >> (32 - r));
  x1 ^= x0;
}

__device__ __forceinline__ uint2 tf2x32(uint32_t k0, uint32_t k1,
                                        uint32_t c0, uint32_t c1) {
  uint32_t k2 = k0 ^ k1 ^ 0x1BD11BDAu;
  uint32_t x0 = c0 + k0, x1 = c1 + k1;
  tfr(x0,x1,13); tfr(x0,x1,15); tfr(x0,x1,26); tfr(x0,x1,6);
  x0 += k1; x1 += k2 + 1u;
  tfr(x0,x1,17); tfr(x0,x1,29); tfr(x0,x1,16); tfr(x0,x1,24);
  x0 += k2; x1 += k0 + 2u;
  tfr(x0,x1,13); tfr(x0,x1,15); tfr(x0,x1,26); tfr(x0,x1,6);
  x0 += k0; x1 += k1 + 3u;
  tfr(x0,x1,17); tfr(x0,x1,29); tfr(x0,x1,16); tfr(x0,x1,24);
  x0 += k1; x1 += k2 + 4u;
  tfr(x0,x1,13); tfr(x0,x1,15); tfr(x0,x1,26); tfr(x0,x1,6);
  x0 += k2; x1 += k0 + 5u;
  return make_uint2(x0, x1);
}

__device__ __forceinline__ float bits_to_unif(uint32_t b) {
  return __uint_as_float((b >> 9) | 0x3f800000u) - 1.0f;
}

__global__ __launch_bounds__(256, 4)
void snn_fused(const float* __restrict__ x,  const float* __restrict__ W1,
               const float* __restrict__ b1, const float* __restrict__ W2,
               const float* __restrict__ b2, float* __restrict__ out) {
  __shared__ uint32_t xib[2][8][XIW];      // 1664 B  (xi bits for t0,t1)
  __shared__ uint32_t spk[2][8][SPW];      // 896 B   (spikes for t0,t1)

  const int tid  = threadIdx.x;            // 0..255
  const int g    = blockIdx.x;             // 0..2047
  const int wv   = tid >> 6;               // wave 0..3
  const int sg   = wv >> 1;                // sample group 0..1 (4 samples)
  const int kh   = wv & 1;                 // neuron half: j base 0 / 256
  const int lane = tid & 63;
  const int jb   = 256 * kh + lane;        // neuron j for k=0

  // per-k W1 row pointers (rows >= 400 clamped to row 0; value never used:
  // bias 0 keeps dummy mem <= garbage but its spike bits are never read)
  const float* gp[4];
#pragma unroll
  for (int k = 0; k < 4; ++k) {
    const int j = jb + 64 * k;
    gp[k] = W1 + (size_t)((j < HID) ? j : 0) * INDIM;
  }

  // biases of owned neurons (dummies 0)
  double bb[4];
#pragma unroll
  for (int k = 0; k < 4; ++k) {
    const int j = jb + 64 * k;
    bb[k] = (j < HID) ? (double)b1[j] : 0.0;
  }

  // persistent layer-1 state: samples 4sg+s, neurons j = jb + 64k
  double   mem1[4][4];
  double   acc1[4][4];
  uint32_t spv[4];
#pragma unroll
  for (int s = 0; s < 4; ++s) {
    spv[s] = 0u;
#pragma unroll
    for (int k = 0; k < 4; ++k) { mem1[s][k] = 0.0; acc1[s][k] = 0.0; }
  }

  // layer-2 ownership: tid<80 -> (sample ls, output lo)
  const int ls = tid / ODIM;
  const int lo = tid - ls * ODIM;
  double m2 = 0.0;
  int    s2 = 0, cnt2 = 0;
  const double b2r = (tid < 80) ? (double)b2[lo] : 0.0;

  // Lean dense layer-2 (V6): one float4 + spike-nibble per iteration,
  // 4 partial f64 dots (f64 reorder safe; fma exact for bit in {0,1}).
  auto layer2_step = [&](int tt) {
    if (tid < 80) {
      double a2 = s2 ? 0.0 : m2 * 0.2;
      double d0 = 0.0, d1 = 0.0, d2 = 0.0, d3 = 0.0;
      const float4* w2p = (const float4*)(W2 + lo * HID);
#pragma unroll 4
      for (int qq = 0; qq < 100; ++qq) {   // j = 4*qq .. 4*qq+3
        const uint32_t nib = (spk[tt][ls][qq >> 3] >> ((qq & 7) * 4)) & 0xFu;
        const float4 v4 = w2p[qq];
        d0 = fma((double)v4.x, (double)(nib & 1u),        d0);
        d1 = fma((double)v4.y, (double)((nib >> 1) & 1u), d1);
        d2 = fma((double)v4.z, (double)((nib >> 2) & 1u), d2);
        d3 = fma((double)v4.w, (double)((nib >> 3) & 1u), d3);
      }
      m2 = (a2 + ((d0 + d1) + (d2 + d3))) + b2r;
      s2 = (m2 > 0.5) ? 1 : 0;
      cnt2 += s2;
    }
  };

  for (int tp = 0; tp < TSTEPS / 2; ++tp) {
    // ---- step keys for the pair ----
    const uint2 ka = tf2x32(0u, 42u, 0u, (uint32_t)(2 * tp));
    const uint2 kb = tf2x32(0u, 42u, 0u, (uint32_t)(2 * tp + 1));
    const uint32_t kx[2] = { ka.x, kb.x };
    const uint32_t ky[2] = { ka.y, kb.y };

    // ---- xi generation for BOTH steps; c-range split across kh pair ----
    const int cA = kh ? 7 : 0;
    const int cB = kh ? 13 : 7;
    for (int s = 0; s < 4; ++s) {
      const int q   = 4 * sg + s;          // block-sample 0..7
      const int row = g * 4 + s + sg * 8192;
      for (int c = cA; c < cB; ++c) {
        const int d = c * 64 + lane;
        const bool valid = (d < INDIM);
        float xv = 0.0f;
        if (valid) xv = x[row * INDIM + d];
        const uint32_t e = (uint32_t)row * (uint32_t)INDIM + (uint32_t)d;
#pragma unroll
        for (int tt = 0; tt < 2; ++tt) {
          int xb = 0;
          if (valid) {
            uint2 r = tf2x32(kx[tt], ky[tt], 0u, e);
            xb = xv > bits_to_unif(r.x ^ r.y);
          }
          unsigned long long m = __ballot(xb);
          if (lane == 0) {
            xib[tt][q][2*c]     = (uint32_t)m;
            xib[tt][q][2*c + 1] = (uint32_t)(m >> 32);
          }
        }
      }
    }
    __syncthreads();                       // xib visible to both kh waves

    // ---- decay + reset into t0 accumulator; zero t1 accumulator ----
#pragma unroll
    for (int s = 0; s < 4; ++s)
#pragma unroll
      for (int k = 0; k < 4; ++k) {
        mem1[s][k] = ((spv[s] >> k) & 1u) ? 0.0 : mem1[s][k] * 0.2;
        acc1[s][k] = 0.0;
      }

    // ---- BARRIER-FREE sweep: W1 read direct from global (L1/L2-hot) ----
    for (int td = 0; td < NT; ++td) {
      // xi bit-bytes for this 8-d chunk, hoisted to SGPR (wave-uniform)
      const int wi = td >> 2, sh = (td & 3) * 8;
      uint32_t bA[4], bB[4];
#pragma unroll
      for (int s = 0; s < 4; ++s) {
        bA[s] = (uint32_t)__builtin_amdgcn_readfirstlane(
                  (int)((xib[0][4*sg + s][wi] >> sh) & 0xFFu));
        bB[s] = (uint32_t)__builtin_amdgcn_readfirstlane(
                  (int)((xib[1][4*sg + s][wi] >> sh) & 0xFFu));
      }

      const int d0 = td * TD;
#pragma unroll
      for (int h = 0; h < 2; ++h) {        // two 4-dt half-chunks
        // batch-issue 16 independent loads (vmcnt-batched, L1-hot lines)
        float wf[4][4];
#pragma unroll
        for (int dt2 = 0; dt2 < 4; ++dt2)
#pragma unroll
          for (int k = 0; k < 4; ++k)
            wf[dt2][k] = gp[k][d0 + 4 * h + dt2];

#pragma unroll
        for (int dt2 = 0; dt2 < 4; ++dt2) {
          const int dt = 4 * h + dt2;
#pragma unroll
          for (int s = 0; s < 4; ++s) {
            if (bA[s] & (1u << dt)) {      // scalar test: s_and + s_cbranch
#pragma unroll
              for (int k = 0; k < 4; ++k)
                mem1[s][k] += (double)wf[dt2][k];
            }
            if (bB[s] & (1u << dt)) {
#pragma unroll
              for (int k = 0; k < 4; ++k)
                acc1[s][k] += (double)wf[dt2][k];
            }
          }
        }
      }
    }

    // ---- finalize t0: + b1, threshold, pack spikes -> spk[0] ----
#pragma unroll
    for (int s = 0; s < 4; ++s) {
      uint32_t m = 0u;
#pragma unroll
      for (int k = 0; k < 4; ++k) {
        mem1[s][k] += bb[k];
        if (mem1[s][k] > 0.5) m |= (1u << k);
      }
      spv[s] = m;
#pragma unroll
      for (int k = 0; k < 4; ++k) {
        unsigned long long bm = __ballot((m >> k) & 1u);
        const int w0 = 8 * kh + 2 * k;
        if (lane == 0 && w0 < SPW) {
          spk[0][4*sg + s][w0]     = (uint32_t)bm;
          spk[0][4*sg + s][w0 + 1] = (uint32_t)(bm >> 32);
        }
      }
    }

    // ---- finalize t1: decay(t0) + acc1 + b1, threshold -> spk[1] ----
#pragma unroll
    for (int s = 0; s < 4; ++s) {
      uint32_t m = 0u;
#pragma unroll
      for (int k = 0; k < 4; ++k) {
        double v = ((spv[s] >> k) & 1u) ? 0.0 : mem1[s][k] * 0.2;
        v += acc1[s][k];
        v += bb[k];
        mem1[s][k] = v;
        if (v > 0.5) m |= (1u << k);
      }
      spv[s] = m;
#pragma unroll
      for (int k = 0; k < 4; ++k) {
        unsigned long long bm = __ballot((m >> k) & 1u);
        const int w0 = 8 * kh + 2 * k;
        if (lane == 0 && w0 < SPW) {
          spk[1][4*sg + s][w0]     = (uint32_t)bm;
          spk[1][4*sg + s][w0 + 1] = (uint32_t)(bm >> 32);
        }
      }
    }
    __syncthreads();                       // spikes(t0,t1) visible

    layer2_step(0);                        // t0
    layer2_step(1);                        // t1
    // no barrier: layer2 overlaps next pair's xi-gen; spk is next written
    // only after the next pair's xib barrier -> ordering safe.
  }

  // ---- output: h2_sum / 20 ----
  if (tid < 80) {
    const int row = g * 4 + (ls & 3) + ((ls >= 4) ? 8192 : 0);
    out[row * ODIM + lo] = (float)((double)cnt2 / 20.0);
  }
}

extern "C" void kernel_launch(void* const* d_in, const int* in_sizes, int n_in,
                              void* d_out, int out_size, void* d_ws, size_t ws_size,
                              hipStream_t stream) {
  const float* x  = (const float*)d_in[0];
  const float* W1 = (const float*)d_in[1];
  const float* b1 = (const float*)d_in[2];
  const float* W2 = (const float*)d_in[3];
  const float* b2 = (const float*)d_in[4];
  // d_in[5] = time_window (int, ==20) — compile-time constant here.
  float* out = (float*)d_out;
  hipLaunchKernelGGL(snn_fused, dim3(2048), dim3(256), 0, stream,
                     x, W1, b1, W2, b2, out);
}

// Round 9
// 3991.322 us; speedup vs baseline: 3.2360x; 2.9415x over previous
//
#include <hip/hip_runtime.h>
#include <stdint.h>

// ---------------------------------------------------------------------------
// Fused spiking-MLP forward: 20 timesteps, B=16384, 784 -> 400 -> 10.
// V10 = V9 (integer-MFMA reformulation) hardened + ws_size gate with the
// verified V6 monolithic kernel (5078us, absmax 0.0) as fallback.
//
// V9 crash audit -> fixes:
//  * d_ws overflow suspected (51.5MB needed, never checked): runtime gate.
//  * limb clamp tightened to balanced-digit representable max (547.6e9).
//  * B-tile LDS stride padded 202->203 dwords (coprime 32, conflict-free).
//  * K1 xi-gen restructured: one wave = one sample, x row loaded once,
//    all 20 timesteps emitted (20x less x traffic).
//
// MFMA pipeline (when ws permits):
//  K1 snn_prep : xi bits [t][s][25 u32] + W1 as 5 balanced signed-i8 limbs
//                of round(W1*2^41)  [l][col][202 u32].
//  K2 snn_l1   : layer-1 dots as exact i8 GEMMs (mfma_i32_32x32x32_i8),
//                recombined in f64 (limb sums <2^17: exact); LIF recurrence
//                f64; spike bits -> ws [s][t][13 u32]. Only deviation vs
//                f64 reference = W1 quantization: ~2e-12 typ, 1.8e-10 max
//                -> expected spike flips ~1e-4 over 1.3e8 decisions.
//  K3 snn_l2   : V6's lean dense fma-gated f64 layer 2 from spike bits.
// ---------------------------------------------------------------------------

#define INDIM  784
#define HID    400
#define ODIM   10
#define TSTEPS 20
#define NS     16384

// V9 geometry
#define KW     25          // xi u32 words per sample (800 bits, pad 0)
#define NCOL   416         // padded neuron cols (13 x 32)
#define NB_N   13
#define BROWG  202         // global dwords per limb row (808 B)
#define BROWL  203         // LDS-padded row stride (coprime 32)
#define MS     256         // samples per l1 block
#define NLIMB  5

// ws layout (dwords)
#define XI_DW   ((size_t)TSTEPS * NS * KW)        // 8,192,000
#define SPK_OFF (XI_DW)
#define SPK_DW  ((size_t)NS * TSTEPS * NB_N)      // 4,259,840
#define BL_OFF  (XI_DW + SPK_DW)
#define WS_NEED ((XI_DW + SPK_DW + (size_t)NLIMB * NCOL * BROWG) * 4)

// V6 geometry
#define TD   8
#define NT   98
#define WTJ  512
#define XIW  26
#define SPW  14

typedef int i32x4  __attribute__((ext_vector_type(4)));
typedef int i32x16 __attribute__((ext_vector_type(16)));

__device__ __forceinline__ void tfr(uint32_t& x0, uint32_t& x1, int r) {
  x0 += x1;
  x1 = (x1 << r) | (x1 >> (32 - r));
  x1 ^= x0;
}

__device__ __forceinline__ uint2 tf2x32(uint32_t k0, uint32_t k1,
                                        uint32_t c0, uint32_t c1) {
  uint32_t k2 = k0 ^ k1 ^ 0x1BD11BDAu;
  uint32_t x0 = c0 + k0, x1 = c1 + k1;
  tfr(x0,x1,13); tfr(x0,x1,15); tfr(x0,x1,26); tfr(x0,x1,6);
  x0 += k1; x1 += k2 + 1u;
  tfr(x0,x1,17); tfr(x0,x1,29); tfr(x0,x1,16); tfr(x0,x1,24);
  x0 += k2; x1 += k0 + 2u;
  tfr(x0,x1,13); tfr(x0,x1,15); tfr(x0,x1,26); tfr(x0,x1,6);
  x0 += k0; x1 += k1 + 3u;
  tfr(x0,x1,17); tfr(x0,x1,29); tfr(x0,x1,16); tfr(x0,x1,24);
  x0 += k1; x1 += k2 + 4u;
  tfr(x0,x1,13); tfr(x0,x1,15); tfr(x0,x1,26); tfr(x0,x1,6);
  x0 += k2; x1 += k0 + 5u;
  return make_uint2(x0, x1);
}

__device__ __forceinline__ float bits_to_unif(uint32_t b) {
  return __uint_as_float((b >> 9) | 0x3f800000u) - 1.0f;
}

// ======================== V9 path ==========================================

// ---- K1: xi bits (one wave per sample, all 20 t) + W1 limb decomposition --
__global__ __launch_bounds__(256, 4)
void snn_prep(const float* __restrict__ x, const float* __restrict__ W1,
              uint32_t* __restrict__ ws) {
  const int tid = threadIdx.x, bid = blockIdx.x;
  if (bid < 4096) {
    const int wv = tid >> 6, lane = tid & 63;
    const int s  = bid * 4 + wv;                     // one sample per wave
    float xv[13];
#pragma unroll
    for (int c = 0; c < 13; ++c) {
      const int d = c * 64 + lane;
      xv[c] = (d < INDIM) ? x[s * INDIM + d] : 0.0f;
    }
    for (int t = 0; t < TSTEPS; ++t) {
      const uint2 kt = tf2x32(0u, 42u, 0u, (uint32_t)t);
      uint32_t* dst = ws + ((size_t)t * NS + s) * KW;
#pragma unroll
      for (int c = 0; c < 13; ++c) {
        const int d = c * 64 + lane;
        int xb = 0;
        if (d < INDIM) {
          uint2 r = tf2x32(kt.x, kt.y, 0u, (uint32_t)(s * INDIM + d));
          xb = xv[c] > bits_to_unif(r.x ^ r.y);
        }
        unsigned long long m = __ballot(xb);
        if (lane == 0) {
          dst[2*c] = (uint32_t)m;
          if (2*c + 1 < KW) dst[2*c + 1] = (uint32_t)(m >> 32);
        }
      }
    }
  } else {
    // W1 limb prep: thread = (col, 4-byte k-group)
    const int idx = (bid - 4096) * 256 + tid;
    if (idx < NCOL * BROWG) {
      const int col = idx / BROWG, grp = idx - col * BROWG;
      uint32_t dw[NLIMB] = {0u, 0u, 0u, 0u, 0u};
#pragma unroll
      for (int b = 0; b < 4; ++b) {
        const int d = grp * 4 + b;
        double w = 0.0;
        if (col < HID && d < INDIM) w = (double)W1[col * INDIM + d];
        long long V = (long long)rint(w * 0x1p41);
        const long long CAP = 547599908735ll;   // 127*(256^5-1)/255
        if (V >  CAP) V =  CAP;
        if (V < -CAP) V = -CAP;
#pragma unroll
        for (int l = 0; l < NLIMB; ++l) {
          const int r = (int)(((V + 128) & 255) - 128);  // balanced digit
          dw[l] |= ((uint32_t)(uint8_t)(int8_t)r) << (8 * b);
          V = (V - r) >> 8;                               // exact
        }
      }
      uint32_t* bl = ws + BL_OFF;
#pragma unroll
      for (int l = 0; l < NLIMB; ++l)
        bl[((size_t)l * NCOL + col) * BROWG + grp] = dw[l];
    }
  }
}

// ---- K2: layer-1 integer GEMM + LIF ---------------------------------------
__global__ __launch_bounds__(256, 2)
void snn_l1(const float* __restrict__ b1, uint32_t* __restrict__ ws) {
  __shared__ uint32_t xi_lds[MS * KW];        // 25,600 B
  __shared__ uint32_t blds[2][32 * BROWL];    // 51,968 B (double-buffered)

  const int tid  = threadIdx.x;
  const int nb   = blockIdx.x % NB_N;         // N-block (32 cols)
  const int mb   = blockIdx.x / NB_N;         // M-block (256 samples)
  const int n0   = nb * 32, sbase = mb * MS;
  const int wv   = tid >> 6, lane = tid & 63;
  const int half = lane >> 5, c31 = lane & 31;
  const int col  = n0 + c31;
  const double bb = (col < HID) ? (double)b1[col] : 0.0;

  const uint32_t* xi_ws  = ws;
  uint32_t*       spk_ws = ws + SPK_OFF;
  const uint32_t* bl_ws  = ws + BL_OFF;

  auto stageB = [&](int l, int buf) {
    if (tid < BROWG) {
      const uint32_t* src = bl_ws + ((size_t)l * NCOL + n0) * BROWG + tid;
      uint32_t* dst = &blds[buf][tid];
#pragma unroll
      for (int c = 0; c < 32; ++c)
        dst[c * BROWL] = src[c * BROWG];
    }
  };
  auto stageXi = [&](int t) {
    const uint32_t* src = xi_ws + ((size_t)t * NS + sbase) * KW;
#pragma unroll
    for (int j = 0; j < KW; ++j)
      xi_lds[tid + j * 256] = src[tid + j * 256];
  };

  // persistent f64 membranes: 2 sample-tiles x 16 C-positions.
  // C layout (HW-verified, dtype-indep): col=lane&31,
  // row=(reg&3)+8*(reg>>2)+4*(lane>>5)
  double mem[2][16];
  uint32_t sp[2] = {0u, 0u};
#pragma unroll
  for (int T = 0; T < 2; ++T)
#pragma unroll
    for (int i = 0; i < 16; ++i) mem[T][i] = 0.0;

  stageB(0, 0);
  stageXi(0);
  __syncthreads();

  int cur = 0;
  for (int t = 0; t < TSTEPS; ++t) {
    // decay + reset (spike from prev step)
#pragma unroll
    for (int T = 0; T < 2; ++T)
#pragma unroll
      for (int i = 0; i < 16; ++i)
        mem[T][i] = ((sp[T] >> i) & 1u) ? 0.0 : mem[T][i] * 0.2;

    double sc = 0x1p-41;                     // limb scale, x256 per limb
    for (int l = 0; l < NLIMB; ++l) {
      stageB((l + 1) % NLIMB, cur ^ 1);      // overlaps this limb's sweep

      i32x16 acc0, acc1;
#pragma unroll
      for (int i = 0; i < 16; ++i) { acc0[i] = 0; acc1[i] = 0; }

      const uint32_t* xr0 = &xi_lds[(wv * 64 +  0 + c31) * KW];
      const uint32_t* xr1 = &xi_lds[(wv * 64 + 32 + c31) * KW];
      const uint32_t* bp0 = &blds[cur][c31 * BROWL + half * 4];

#pragma unroll 5
      for (int ks = 0; ks < 25; ++ks) {
        // A-frags: 16 k-bits -> 16 bytes (0/1), nibble-spread (carry-free)
        const uint32_t hw0 = (xr0[ks] >> (16 * half)) & 0xFFFFu;
        const uint32_t hw1 = (xr1[ks] >> (16 * half)) & 0xFFFFu;
        i32x4 a0, a1, bfr;
#pragma unroll
        for (int q = 0; q < 4; ++q) {
          a0[q] = (int)((((hw0 >> (4*q)) & 0xFu) * 0x00204081u) & 0x01010101u);
          a1[q] = (int)((((hw1 >> (4*q)) & 0xFu) * 0x00204081u) & 0x01010101u);
        }
        // B-frag: 16 limb bytes, contiguous k (2x ds_read_b64)
        const uint32_t* bp = bp0 + ks * 8;
        const uint2 p0 = *(const uint2*)(bp);
        const uint2 p1 = *(const uint2*)(bp + 2);
        bfr[0] = (int)p0.x; bfr[1] = (int)p0.y;
        bfr[2] = (int)p1.x; bfr[3] = (int)p1.y;
        acc0 = __builtin_amdgcn_mfma_i32_32x32x32_i8(a0, bfr, acc0, 0, 0, 0);
        acc1 = __builtin_amdgcn_mfma_i32_32x32x32_i8(a1, bfr, acc1, 0, 0, 0);
      }

      // recombine limb sums (acc*sc exact: |acc|<2^17, sc=2^e)
#pragma unroll
      for (int i = 0; i < 16; ++i) {
        mem[0][i] += (double)acc0[i] * sc;
        mem[1][i] += (double)acc1[i] * sc;
      }
      sc *= 256.0;
      __syncthreads();                       // dbuf swap ready
      cur ^= 1;
    }

    // bias + threshold
    uint32_t m0 = 0u, m1 = 0u;
#pragma unroll
    for (int i = 0; i < 16; ++i) {
      mem[0][i] += bb;  if (mem[0][i] > 0.5) m0 |= (1u << i);
      mem[1][i] += bb;  if (mem[1][i] > 0.5) m1 |= (1u << i);
    }
    sp[0] = m0; sp[1] = m1;

    // pack spike bits: low ballot = row rlo, high = row rlo+4 (cols 0..31)
#pragma unroll
    for (int T = 0; T < 2; ++T) {
      const uint32_t mm = T ? m1 : m0;
#pragma unroll
      for (int rg = 0; rg < 16; ++rg) {
        unsigned long long bm = __ballot((mm >> rg) & 1u);
        if (lane == 0) {
          const int rlo  = (rg & 3) + 8 * (rg >> 2);
          const int srow = sbase + wv * 64 + T * 32 + rlo;
          spk_ws[((size_t)srow * TSTEPS + t) * NB_N + nb] = (uint32_t)bm;
          spk_ws[((size_t)(srow + 4) * TSTEPS + t) * NB_N + nb] =
              (uint32_t)(bm >> 32);
        }
      }
    }

    if (t + 1 < TSTEPS) stageXi(t + 1);      // xi(t) dead after limb-4 barrier
    __syncthreads();
  }
}

// ---- K3: layer-2 LIF + output (V6's validated lean form) ------------------
__global__ __launch_bounds__(256, 4)
void snn_l2(const float* __restrict__ W2, const float* __restrict__ b2,
            const uint32_t* __restrict__ ws, float* __restrict__ out) {
  const int gid    = blockIdx.x * 256 + threadIdx.x;   // < 163840
  const int sample = gid / ODIM;
  const int oc     = gid - sample * ODIM;
  const uint32_t* spk_ws = ws + SPK_OFF;

  double m2 = 0.0; int s2 = 0, cnt2 = 0;
  const double b2r = (double)b2[oc];
  const float4* w2p = (const float4*)(W2 + oc * HID);

  for (int t = 0; t < TSTEPS; ++t) {
    const uint32_t* sw = spk_ws + ((size_t)sample * TSTEPS + t) * NB_N;
    const double a2 = s2 ? 0.0 : m2 * 0.2;
    double d0 = 0.0, d1 = 0.0, d2 = 0.0, d3 = 0.0;
#pragma unroll 2
    for (int w = 0; w < 12; ++w) {           // j 0..383
      const uint32_t word = sw[w];
#pragma unroll
      for (int q = 0; q < 8; ++q) {
        const float4 v4 = w2p[8 * w + q];
        const uint32_t nib = (word >> (4 * q)) & 0xFu;
        d0 = fma((double)v4.x, (double)(nib & 1u),        d0);
        d1 = fma((double)v4.y, (double)((nib >> 1) & 1u), d1);
        d2 = fma((double)v4.z, (double)((nib >> 2) & 1u), d2);
        d3 = fma((double)v4.w, (double)((nib >> 3) & 1u), d3);
      }
    }
    {                                        // word 12: j 384..399
      const uint32_t word = sw[12] & 0xFFFFu;
#pragma unroll
      for (int q = 0; q < 4; ++q) {
        const float4 v4 = w2p[96 + q];
        const uint32_t nib = (word >> (4 * q)) & 0xFu;
        d0 = fma((double)v4.x, (double)(nib & 1u),        d0);
        d1 = fma((double)v4.y, (double)((nib >> 1) & 1u), d1);
        d2 = fma((double)v4.z, (double)((nib >> 2) & 1u), d2);
        d3 = fma((double)v4.w, (double)((nib >> 3) & 1u), d3);
      }
    }
    m2 = (a2 + ((d0 + d1) + (d2 + d3))) + b2r;
    s2 = (m2 > 0.5) ? 1 : 0;
    cnt2 += s2;
  }
  out[sample * ODIM + oc] = (float)((double)cnt2 / 20.0);
}

// ======================== V6 fallback (verified 5078us) ====================
__global__ __launch_bounds__(512, 4)
void snn_fused_v6(const float* __restrict__ x,  const float* __restrict__ W1,
                  const float* __restrict__ b1, const float* __restrict__ W2,
                  const float* __restrict__ b2, float* __restrict__ out) {
  __shared__ double   wt[2][TD * WTJ];
  __shared__ uint32_t xib[2][16][XIW];
  __shared__ uint32_t spk[2][16][SPW];

  const int tid  = threadIdx.x;
  const int g    = blockIdx.x;
  const int wv   = tid >> 6;
  const int sg   = wv >> 1;
  const int kh   = wv & 1;
  const int lane = tid & 63;
  const int jb   = 256 * kh + lane;

  for (int i = tid; i < 2 * TD * WTJ; i += 512)
    if ((i & (WTJ - 1)) >= HID) (&wt[0][0])[i] = 0.0;

  double bb[4];
#pragma unroll
  for (int k = 0; k < 4; ++k) {
    const int j = jb + 64 * k;
    bb[k] = (j < HID) ? (double)b1[j] : 0.0;
  }

  double   mem1[4][4];
  double   acc1[4][4];
  uint32_t spv[4];
#pragma unroll
  for (int s = 0; s < 4; ++s) {
    spv[s] = 0u;
#pragma unroll
    for (int k = 0; k < 4; ++k) { mem1[s][k] = 0.0; acc1[s][k] = 0.0; }
  }

  const int ls = tid / ODIM;
  const int lo = tid - ls * ODIM;
  double m2 = 0.0;
  int    s2 = 0, cnt2 = 0;
  const double b2r = (tid < 160) ? (double)b2[lo] : 0.0;

  auto layer2_step = [&](int tt) {
    if (tid < 160) {
      double a2 = s2 ? 0.0 : m2 * 0.2;
      double d0 = 0.0, d1 = 0.0, d2 = 0.0, d3 = 0.0;
      const float4* w2p = (const float4*)(W2 + lo * HID);
#pragma unroll 4
      for (int qq = 0; qq < 100; ++qq) {
        const uint32_t nib = (spk[tt][ls][qq >> 3] >> ((qq & 7) * 4)) & 0xFu;
        const float4 v4 = w2p[qq];
        d0 = fma((double)v4.x, (double)(nib & 1u),        d0);
        d1 = fma((double)v4.y, (double)((nib >> 1) & 1u), d1);
        d2 = fma((double)v4.z, (double)((nib >> 2) & 1u), d2);
        d3 = fma((double)v4.w, (double)((nib >> 3) & 1u), d3);
      }
      m2 = (a2 + ((d0 + d1) + (d2 + d3))) + b2r;
      s2 = (m2 > 0.5) ? 1 : 0;
      cnt2 += s2;
    }
  };

  const bool stager = (tid < HID);
  float4 va = make_float4(0,0,0,0), vb = va;
  if (stager) {
    const float4* s0 = (const float4*)(W1 + tid * INDIM);
    va = s0[0]; vb = s0[1];
    double* dst = &wt[0][tid];
    dst[0*WTJ] = (double)va.x;  dst[1*WTJ] = (double)va.y;
    dst[2*WTJ] = (double)va.z;  dst[3*WTJ] = (double)va.w;
    dst[4*WTJ] = (double)vb.x;  dst[5*WTJ] = (double)vb.y;
    dst[6*WTJ] = (double)vb.z;  dst[7*WTJ] = (double)vb.w;
    const float4* s1 = (const float4*)(W1 + tid * INDIM + TD);
    va = s1[0]; vb = s1[1];
  }
  int cur = 0;
  int ld  = 2;
  __syncthreads();

  for (int tp = 0; tp < TSTEPS / 2; ++tp) {
    const uint2 ka = tf2x32(0u, 42u, 0u, (uint32_t)(2 * tp));
    const uint2 kb = tf2x32(0u, 42u, 0u, (uint32_t)(2 * tp + 1));
    const uint32_t kx[2] = { ka.x, kb.x };
    const uint32_t ky[2] = { ka.y, kb.y };

    const int cA = kh ? 7 : 0;
    const int cB = kh ? 13 : 7;
    for (int s = 0; s < 4; ++s) {
      const int q   = 4 * sg + s;
      const int row = g * 8 + (q & 7) + ((q >= 8) ? 8192 : 0);
      for (int c = cA; c < cB; ++c) {
        const int d = c * 64 + lane;
        const bool valid = (d < INDIM);
        float xv = 0.0f;
        if (valid) xv = x[row * INDIM + d];
        const uint32_t e = (uint32_t)row * (uint32_t)INDIM + (uint32_t)d;
#pragma unroll
        for (int tt = 0; tt < 2; ++tt) {
          int xb = 0;
          if (valid) {
            uint2 r = tf2x32(kx[tt], ky[tt], 0u, e);
            xb = xv > bits_to_unif(r.x ^ r.y);
          }
          unsigned long long m = __ballot(xb);
          if (lane == 0) {
            xib[tt][q][2*c]     = (uint32_t)m;
            xib[tt][q][2*c + 1] = (uint32_t)(m >> 32);
          }
        }
      }
    }
    __syncthreads();

#pragma unroll
    for (int s = 0; s < 4; ++s)
#pragma unroll
      for (int k = 0; k < 4; ++k) {
        mem1[s][k] = ((spv[s] >> k) & 1u) ? 0.0 : mem1[s][k] * 0.2;
        acc1[s][k] = 0.0;
      }

    for (int td = 0; td < NT; ++td) {
      if (stager) {
        double* dst = &wt[cur ^ 1][tid];
        dst[0*WTJ] = (double)va.x;  dst[1*WTJ] = (double)va.y;
        dst[2*WTJ] = (double)va.z;  dst[3*WTJ] = (double)va.w;
        dst[4*WTJ] = (double)vb.x;  dst[5*WTJ] = (double)vb.y;
        dst[6*WTJ] = (double)vb.z;  dst[7*WTJ] = (double)vb.w;
        const float4* src = (const float4*)(W1 + tid * INDIM + ld * TD);
        va = src[0]; vb = src[1];
      }
      ld = (ld + 1 == NT) ? 0 : ld + 1;

      const int wi = td >> 2, sh = (td & 3) * 8;
      uint32_t bA[4], bB[4];
#pragma unroll
      for (int s = 0; s < 4; ++s) {
        bA[s] = (uint32_t)__builtin_amdgcn_readfirstlane(
                  (int)((xib[0][4*sg + s][wi] >> sh) & 0xFFu));
        bB[s] = (uint32_t)__builtin_amdgcn_readfirstlane(
                  (int)((xib[1][4*sg + s][wi] >> sh) & 0xFFu));
      }

      const double* wp = &wt[cur][jb];
#pragma unroll
      for (int dt = 0; dt < TD; ++dt) {
        double wd[4];
#pragma unroll
        for (int k = 0; k < 4; ++k)
          wd[k] = wp[dt * WTJ + 64 * k];
#pragma unroll
        for (int s = 0; s < 4; ++s) {
          if (bA[s] & (1u << dt)) {
#pragma unroll
            for (int k = 0; k < 4; ++k) mem1[s][k] += wd[k];
          }
          if (bB[s] & (1u << dt)) {
#pragma unroll
            for (int k = 0; k < 4; ++k) acc1[s][k] += wd[k];
          }
        }
      }

      __syncthreads();
      cur ^= 1;
    }

#pragma unroll
    for (int s = 0; s < 4; ++s) {
      uint32_t m = 0u;
#pragma unroll
      for (int k = 0; k < 4; ++k) {
        mem1[s][k] += bb[k];
        if (mem1[s][k] > 0.5) m |= (1u << k);
      }
      spv[s] = m;
#pragma unroll
      for (int k = 0; k < 4; ++k) {
        unsigned long long bm = __ballot((m >> k) & 1u);
        const int w0 = 8 * kh + 2 * k;
        if (lane == 0 && w0 < SPW) {
          spk[0][4*sg + s][w0]     = (uint32_t)bm;
          spk[0][4*sg + s][w0 + 1] = (uint32_t)(bm >> 32);
        }
      }
    }

#pragma unroll
    for (int s = 0; s < 4; ++s) {
      uint32_t m = 0u;
#pragma unroll
      for (int k = 0; k < 4; ++k) {
        double v = ((spv[s] >> k) & 1u) ? 0.0 : mem1[s][k] * 0.2;
        v += acc1[s][k];
        v += bb[k];
        mem1[s][k] = v;
        if (v > 0.5) m |= (1u << k);
      }
      spv[s] = m;
#pragma unroll
      for (int k = 0; k < 4; ++k) {
        unsigned long long bm = __ballot((m >> k) & 1u);
        const int w0 = 8 * kh + 2 * k;
        if (lane == 0 && w0 < SPW) {
          spk[1][4*sg + s][w0]     = (uint32_t)bm;
          spk[1][4*sg + s][w0 + 1] = (uint32_t)(bm >> 32);
        }
      }
    }
    __syncthreads();

    layer2_step(0);
    layer2_step(1);
  }

  if (tid < 160) {
    const int row = g * 8 + (ls & 7) + ((ls >= 8) ? 8192 : 0);
    out[row * ODIM + lo] = (float)((double)cnt2 / 20.0);
  }
}

// ======================== launch ===========================================
extern "C" void kernel_launch(void* const* d_in, const int* in_sizes, int n_in,
                              void* d_out, int out_size, void* d_ws, size_t ws_size,
                              hipStream_t stream) {
  const float* x  = (const float*)d_in[0];
  const float* W1 = (const float*)d_in[1];
  const float* b1 = (const float*)d_in[2];
  const float* W2 = (const float*)d_in[3];
  const float* b2 = (const float*)d_in[4];
  // d_in[5] = time_window (int, ==20) — compile-time constant here.
  float* out = (float*)d_out;

  if (d_ws != nullptr && ws_size >= WS_NEED) {
    uint32_t* ws = (uint32_t*)d_ws;
    hipLaunchKernelGGL(snn_prep, dim3(4096 + 329), dim3(256), 0, stream,
                       x, W1, ws);
    hipLaunchKernelGGL(snn_l1, dim3(NB_N * 64), dim3(256), 0, stream, b1, ws);
    hipLaunchKernelGGL(snn_l2, dim3(640), dim3(256), 0, stream, W2, b2, ws, out);
  } else {
    hipLaunchKernelGGL(snn_fused_v6, dim3(1024), dim3(512), 0, stream,
                       x, W1, b1, W2, b2, out);
  }
}

// Round 10
// 3476.991 us; speedup vs baseline: 3.7147x; 1.1479x over previous
//
#include <hip/hip_runtime.h>
#include <stdint.h>

// ---------------------------------------------------------------------------
// Fused spiking-MLP forward: 20 timesteps, B=16384, 784 -> 400 -> 10.
// V11: integer-MFMA pipeline, snn_l1 restructured from V10's measured stalls.
//
// V10 counters (l1 = 3050us of 3991): MfmaUtil 7%, VALU 17%, Occ 18.5% ->
// 75% stall. Causes: per-limb stageB load->wait->write chain exposed ~30K
// cyc HBM latency (B evicted from L2 by the 426MB redundant xi stream);
// 13x xi re-read (FETCH 340MB); scattered dword spike stores (WRITE 205MB
// = 16x amplification). V11:
//  * ALL 5 B-limbs resident in LDS (129.9KB, loaded once; no staging in
//    the t-loop). LDS total 156.5KB -> 1 block/CU, launch_bounds(256,1)
//    -> full 512-reg budget (acc[5][2] i32x16 + mem f64, no spill).
//  * ks-outer/limb-inner: A expanded once per ks for all 5 limbs (5x less
//    VALU). i32 adds order-free; f64 recombine ascending-l unchanged ->
//    bit-identical to V10 (absmax 0.0 verified).
//  * xi reg-prefetch pipeline (t+2 -> regs -> LDS), 2 barriers/t.
//  * spikes collected in LDS, written COALESCED, layout [nb][t][sample];
//    K3 reads updated.
//  * XCD swizzle: 13 nb-blocks of one mb share bid%8 -> same XCD L2 ->
//    xi slab fetched from HBM once, 12x L2 hits.
// ---------------------------------------------------------------------------

#define INDIM  784
#define HID    400
#define ODIM   10
#define TSTEPS 20
#define NS     16384

#define KW     25          // xi u32 words per sample (800 bits, pad 0)
#define NCOL   416         // padded neuron cols (13 x 32)
#define NB_N   13
#define BROWG  202         // global dwords per limb row (808 B)
#define BROWL  203         // LDS-padded row stride (coprime 32)
#define MS     256         // samples per l1 block
#define NLIMB  5

// ws layout (dwords)
#define XI_DW   ((size_t)TSTEPS * NS * KW)        // 8,192,000
#define SPK_OFF (XI_DW)
#define SPK_DW  ((size_t)NS * TSTEPS * NB_N)      // 4,259,840
#define BL_OFF  (XI_DW + SPK_DW)
#define WS_NEED ((XI_DW + SPK_DW + (size_t)NLIMB * NCOL * BROWG) * 4)

// V6 fallback geometry
#define TD   8
#define NT   98
#define WTJ  512
#define XIW  26
#define SPW  14

typedef int i32x4  __attribute__((ext_vector_type(4)));
typedef int i32x16 __attribute__((ext_vector_type(16)));

__device__ __forceinline__ void tfr(uint32_t& x0, uint32_t& x1, int r) {
  x0 += x1;
  x1 = (x1 << r) | (x1 >> (32 - r));
  x1 ^= x0;
}

__device__ __forceinline__ uint2 tf2x32(uint32_t k0, uint32_t k1,
                                        uint32_t c0, uint32_t c1) {
  uint32_t k2 = k0 ^ k1 ^ 0x1BD11BDAu;
  uint32_t x0 = c0 + k0, x1 = c1 + k1;
  tfr(x0,x1,13); tfr(x0,x1,15); tfr(x0,x1,26); tfr(x0,x1,6);
  x0 += k1; x1 += k2 + 1u;
  tfr(x0,x1,17); tfr(x0,x1,29); tfr(x0,x1,16); tfr(x0,x1,24);
  x0 += k2; x1 += k0 + 2u;
  tfr(x0,x1,13); tfr(x0,x1,15); tfr(x0,x1,26); tfr(x0,x1,6);
  x0 += k0; x1 += k1 + 3u;
  tfr(x0,x1,17); tfr(x0,x1,29); tfr(x0,x1,16); tfr(x0,x1,24);
  x0 += k1; x1 += k2 + 4u;
  tfr(x0,x1,13); tfr(x0,x1,15); tfr(x0,x1,26); tfr(x0,x1,6);
  x0 += k2; x1 += k0 + 5u;
  return make_uint2(x0, x1);
}

__device__ __forceinline__ float bits_to_unif(uint32_t b) {
  return __uint_as_float((b >> 9) | 0x3f800000u) - 1.0f;
}

// ======================== MFMA path ========================================

// ---- K1: xi bits (one wave per sample, all 20 t) + W1 limb decomposition --
__global__ __launch_bounds__(256, 4)
void snn_prep(const float* __restrict__ x, const float* __restrict__ W1,
              uint32_t* __restrict__ ws) {
  const int tid = threadIdx.x, bid = blockIdx.x;
  if (bid < 4096) {
    const int wv = tid >> 6, lane = tid & 63;
    const int s  = bid * 4 + wv;                     // one sample per wave
    float xv[13];
#pragma unroll
    for (int c = 0; c < 13; ++c) {
      const int d = c * 64 + lane;
      xv[c] = (d < INDIM) ? x[s * INDIM + d] : 0.0f;
    }
    for (int t = 0; t < TSTEPS; ++t) {
      const uint2 kt = tf2x32(0u, 42u, 0u, (uint32_t)t);
      uint32_t* dst = ws + ((size_t)t * NS + s) * KW;
#pragma unroll
      for (int c = 0; c < 13; ++c) {
        const int d = c * 64 + lane;
        int xb = 0;
        if (d < INDIM) {
          uint2 r = tf2x32(kt.x, kt.y, 0u, (uint32_t)(s * INDIM + d));
          xb = xv[c] > bits_to_unif(r.x ^ r.y);
        }
        unsigned long long m = __ballot(xb);
        if (lane == 0) {
          dst[2*c] = (uint32_t)m;
          if (2*c + 1 < KW) dst[2*c + 1] = (uint32_t)(m >> 32);
        }
      }
    }
  } else {
    // W1 limb prep: thread = (col, 4-byte k-group)
    const int idx = (bid - 4096) * 256 + tid;
    if (idx < NCOL * BROWG) {
      const int col = idx / BROWG, grp = idx - col * BROWG;
      uint32_t dw[NLIMB] = {0u, 0u, 0u, 0u, 0u};
#pragma unroll
      for (int b = 0; b < 4; ++b) {
        const int d = grp * 4 + b;
        double w = 0.0;
        if (col < HID && d < INDIM) w = (double)W1[col * INDIM + d];
        long long V = (long long)rint(w * 0x1p41);
        const long long CAP = 547599908735ll;   // 127*(256^5-1)/255
        if (V >  CAP) V =  CAP;
        if (V < -CAP) V = -CAP;
#pragma unroll
        for (int l = 0; l < NLIMB; ++l) {
          const int r = (int)(((V + 128) & 255) - 128);  // balanced digit
          dw[l] |= ((uint32_t)(uint8_t)(int8_t)r) << (8 * b);
          V = (V - r) >> 8;                               // exact
        }
      }
      uint32_t* bl = ws + BL_OFF;
#pragma unroll
      for (int l = 0; l < NLIMB; ++l)
        bl[((size_t)l * NCOL + col) * BROWG + grp] = dw[l];
    }
  }
}

// ---- K2: layer-1 integer GEMM + LIF (B fully LDS-resident) ----------------
__global__ __launch_bounds__(256, 1)
void snn_l1(const float* __restrict__ b1, uint32_t* __restrict__ ws) {
  __shared__ uint32_t blds[NLIMB][32 * BROWL];   // 129,920 B (all limbs)
  __shared__ uint32_t xi_lds[MS * KW];           // 25,600 B
  __shared__ uint32_t spkbuf[MS];                // 1,024 B

  const int tid = threadIdx.x;
  // XCD swizzle: the 13 nb-blocks of one mb share bid%8 -> same XCD
  const int bid = blockIdx.x;                    // 0..831 = 8 * 13 * 8
  const int x8  = bid & 7;
  const int q   = bid >> 3;                      // 0..103
  const int nb  = q % NB_N;
  const int mb  = x8 + 8 * (q / NB_N);           // 0..63
  const int n0  = nb * 32, sbase = mb * MS;
  const int wv  = tid >> 6, lane = tid & 63;
  const int half = lane >> 5, c31 = lane & 31;
  const int col = n0 + c31;
  const double bb = (col < HID) ? (double)b1[col] : 0.0;

  const uint32_t* xi_ws  = ws;
  uint32_t*       spk_ws = ws + SPK_OFF;
  const uint32_t* bl_ws  = ws + BL_OFF;

  // ---- preload ALL 5 B-limbs into LDS (once) ----
  for (int i = tid; i < NLIMB * 32 * BROWG; i += 256) {
    const int l  = i / (32 * BROWG);
    const int r  = i - l * (32 * BROWG);
    const int c  = r / BROWG;
    const int gd = r - c * BROWG;
    blds[l][c * BROWL + gd] =
        bl_ws[((size_t)l * NCOL + n0 + c) * BROWG + gd];
  }
  // ---- xi(0) -> LDS; prefetch xi(1) -> regs ----
  {
    const uint32_t* src = xi_ws + ((size_t)0 * NS + sbase) * KW;
#pragma unroll
    for (int j = 0; j < KW; ++j)
      xi_lds[tid + j * 256] = src[tid + j * 256];
  }
  uint32_t pf[KW];
  {
    const uint32_t* src = xi_ws + ((size_t)1 * NS + sbase) * KW;
#pragma unroll
    for (int j = 0; j < KW; ++j) pf[j] = src[tid + j * 256];
  }
  __syncthreads();

  // persistent f64 membranes: 2 sample-tiles x 16 C-positions.
  // C layout (HW-verified): col=lane&31, row=(reg&3)+8*(reg>>2)+4*(lane>>5)
  double mem[2][16];
  uint32_t sp[2] = {0u, 0u};
#pragma unroll
  for (int T = 0; T < 2; ++T)
#pragma unroll
    for (int i = 0; i < 16; ++i) mem[T][i] = 0.0;

  const uint32_t* xr0 = &xi_lds[(wv * 64 +  0 + c31) * KW];
  const uint32_t* xr1 = &xi_lds[(wv * 64 + 32 + c31) * KW];
  const uint32_t* bb0 = &blds[0][c31 * BROWL + half * 4];

  for (int t = 0; t < TSTEPS; ++t) {
    // decay + reset
#pragma unroll
    for (int T = 0; T < 2; ++T)
#pragma unroll
      for (int i = 0; i < 16; ++i)
        mem[T][i] = ((sp[T] >> i) & 1u) ? 0.0 : mem[T][i] * 0.2;

    i32x16 acc[NLIMB][2];
#pragma unroll
    for (int l = 0; l < NLIMB; ++l)
#pragma unroll
      for (int T = 0; T < 2; ++T)
#pragma unroll
        for (int i = 0; i < 16; ++i) acc[l][T][i] = 0;

    // ks-outer / limb-inner: A expanded once, feeds 5 limbs
#pragma unroll 5
    for (int ks = 0; ks < 25; ++ks) {
      const uint32_t hw0 = (xr0[ks] >> (16 * half)) & 0xFFFFu;
      const uint32_t hw1 = (xr1[ks] >> (16 * half)) & 0xFFFFu;
      i32x4 a0, a1;
#pragma unroll
      for (int qq = 0; qq < 4; ++qq) {
        a0[qq] = (int)((((hw0 >> (4*qq)) & 0xFu) * 0x00204081u) & 0x01010101u);
        a1[qq] = (int)((((hw1 >> (4*qq)) & 0xFu) * 0x00204081u) & 0x01010101u);
      }
#pragma unroll
      for (int l = 0; l < NLIMB; ++l) {
        const uint32_t* bp = bb0 + l * (32 * BROWL) + ks * 8;
        const uint2 p0 = *(const uint2*)(bp);
        const uint2 p1 = *(const uint2*)(bp + 2);
        i32x4 bfr;
        bfr[0] = (int)p0.x; bfr[1] = (int)p0.y;
        bfr[2] = (int)p1.x; bfr[3] = (int)p1.y;
        acc[l][0] = __builtin_amdgcn_mfma_i32_32x32x32_i8(a0, bfr, acc[l][0],
                                                          0, 0, 0);
        acc[l][1] = __builtin_amdgcn_mfma_i32_32x32x32_i8(a1, bfr, acc[l][1],
                                                          0, 0, 0);
      }
    }

    // recombine limbs ascending (acc*sc exact: |acc|<2^17, sc=2^e)
    double sc = 0x1p-41;
#pragma unroll
    for (int l = 0; l < NLIMB; ++l) {
#pragma unroll
      for (int i = 0; i < 16; ++i) {
        mem[0][i] += (double)acc[l][0][i] * sc;
        mem[1][i] += (double)acc[l][1][i] * sc;
      }
      sc *= 256.0;
    }

    // bias + threshold
    uint32_t m0 = 0u, m1 = 0u;
#pragma unroll
    for (int i = 0; i < 16; ++i) {
      mem[0][i] += bb;  if (mem[0][i] > 0.5) m0 |= (1u << i);
      mem[1][i] += bb;  if (mem[1][i] > 0.5) m1 |= (1u << i);
    }
    sp[0] = m0; sp[1] = m1;

    // pack spike words into LDS (then coalesced global write)
#pragma unroll
    for (int T = 0; T < 2; ++T) {
      const uint32_t mm = T ? m1 : m0;
#pragma unroll
      for (int rg = 0; rg < 16; ++rg) {
        unsigned long long bm = __ballot((mm >> rg) & 1u);
        if (lane == 0) {
          const int rlo = (rg & 3) + 8 * (rg >> 2);
          const int sl  = wv * 64 + T * 32 + rlo;
          spkbuf[sl]     = (uint32_t)bm;
          spkbuf[sl + 4] = (uint32_t)(bm >> 32);
        }
      }
    }
    __syncthreads();                     // compute done; spkbuf ready

    // coalesced spike write: layout [nb][t][sample]
    spk_ws[((size_t)nb * TSTEPS + t) * NS + sbase + tid] = spkbuf[tid];

    if (t + 1 < TSTEPS) {
      // xi(t+1): regs -> LDS; issue loads for t+2
#pragma unroll
      for (int j = 0; j < KW; ++j) xi_lds[tid + j * 256] = pf[j];
      const int tn = (t + 2 < TSTEPS) ? t + 2 : TSTEPS - 1;
      const uint32_t* src = xi_ws + ((size_t)tn * NS + sbase) * KW;
#pragma unroll
      for (int j = 0; j < KW; ++j) pf[j] = src[tid + j * 256];
      __syncthreads();                   // xi(t+1) visible
    }
  }
}

// ---- K3: layer-2 LIF + output (lean fma-gated f64; new spk layout) --------
__global__ __launch_bounds__(256, 4)
void snn_l2(const float* __restrict__ W2, const float* __restrict__ b2,
            const uint32_t* __restrict__ ws, float* __restrict__ out) {
  const int gid    = blockIdx.x * 256 + threadIdx.x;   // < 163840
  const int sample = gid / ODIM;
  const int oc     = gid - sample * ODIM;
  const uint32_t* spk_ws = ws + SPK_OFF;

  double m2 = 0.0; int s2 = 0, cnt2 = 0;
  const double b2r = (double)b2[oc];
  const float4* w2p = (const float4*)(W2 + oc * HID);

  for (int t = 0; t < TSTEPS; ++t) {
    // batch the 13 spike words (independent loads)
    uint32_t sw[NB_N];
#pragma unroll
    for (int w = 0; w < NB_N; ++w)
      sw[w] = spk_ws[((size_t)w * TSTEPS + t) * NS + sample];
    sw[12] &= 0xFFFFu;

    const double a2 = s2 ? 0.0 : m2 * 0.2;
    double d0 = 0.0, d1 = 0.0, d2 = 0.0, d3 = 0.0;
#pragma unroll 2
    for (int w = 0; w < 12; ++w) {           // j 0..383
      const uint32_t word = sw[w];
#pragma unroll
      for (int qq = 0; qq < 8; ++qq) {
        const float4 v4 = w2p[8 * w + qq];
        const uint32_t nib = (word >> (4 * qq)) & 0xFu;
        d0 = fma((double)v4.x, (double)(nib & 1u),        d0);
        d1 = fma((double)v4.y, (double)((nib >> 1) & 1u), d1);
        d2 = fma((double)v4.z, (double)((nib >> 2) & 1u), d2);
        d3 = fma((double)v4.w, (double)((nib >> 3) & 1u), d3);
      }
    }
    {                                        // j 384..399
      const uint32_t word = sw[12];
#pragma unroll
      for (int qq = 0; qq < 4; ++qq) {
        const float4 v4 = w2p[96 + qq];
        const uint32_t nib = (word >> (4 * qq)) & 0xFu;
        d0 = fma((double)v4.x, (double)(nib & 1u),        d0);
        d1 = fma((double)v4.y, (double)((nib >> 1) & 1u), d1);
        d2 = fma((double)v4.z, (double)((nib >> 2) & 1u), d2);
        d3 = fma((double)v4.w, (double)((nib >> 3) & 1u), d3);
      }
    }
    m2 = (a2 + ((d0 + d1) + (d2 + d3))) + b2r;
    s2 = (m2 > 0.5) ? 1 : 0;
    cnt2 += s2;
  }
  out[sample * ODIM + oc] = (float)((double)cnt2 / 20.0);
}

// ======================== V6 fallback (verified 5078us) ====================
__global__ __launch_bounds__(512, 4)
void snn_fused_v6(const float* __restrict__ x,  const float* __restrict__ W1,
                  const float* __restrict__ b1, const float* __restrict__ W2,
                  const float* __restrict__ b2, float* __restrict__ out) {
  __shared__ double   wt[2][TD * WTJ];
  __shared__ uint32_t xib[2][16][XIW];
  __shared__ uint32_t spk[2][16][SPW];

  const int tid  = threadIdx.x;
  const int g    = blockIdx.x;
  const int wv   = tid >> 6;
  const int sg   = wv >> 1;
  const int kh   = wv & 1;
  const int lane = tid & 63;
  const int jb   = 256 * kh + lane;

  for (int i = tid; i < 2 * TD * WTJ; i += 512)
    if ((i & (WTJ - 1)) >= HID) (&wt[0][0])[i] = 0.0;

  double bb[4];
#pragma unroll
  for (int k = 0; k < 4; ++k) {
    const int j = jb + 64 * k;
    bb[k] = (j < HID) ? (double)b1[j] : 0.0;
  }

  double   mem1[4][4];
  double   acc1[4][4];
  uint32_t spv[4];
#pragma unroll
  for (int s = 0; s < 4; ++s) {
    spv[s] = 0u;
#pragma unroll
    for (int k = 0; k < 4; ++k) { mem1[s][k] = 0.0; acc1[s][k] = 0.0; }
  }

  const int ls = tid / ODIM;
  const int lo = tid - ls * ODIM;
  double m2 = 0.0;
  int    s2 = 0, cnt2 = 0;
  const double b2r = (tid < 160) ? (double)b2[lo] : 0.0;

  auto layer2_step = [&](int tt) {
    if (tid < 160) {
      double a2 = s2 ? 0.0 : m2 * 0.2;
      double d0 = 0.0, d1 = 0.0, d2 = 0.0, d3 = 0.0;
      const float4* w2p = (const float4*)(W2 + lo * HID);
#pragma unroll 4
      for (int qq = 0; qq < 100; ++qq) {
        const uint32_t nib = (spk[tt][ls][qq >> 3] >> ((qq & 7) * 4)) & 0xFu;
        const float4 v4 = w2p[qq];
        d0 = fma((double)v4.x, (double)(nib & 1u),        d0);
        d1 = fma((double)v4.y, (double)((nib >> 1) & 1u), d1);
        d2 = fma((double)v4.z, (double)((nib >> 2) & 1u), d2);
        d3 = fma((double)v4.w, (double)((nib >> 3) & 1u), d3);
      }
      m2 = (a2 + ((d0 + d1) + (d2 + d3))) + b2r;
      s2 = (m2 > 0.5) ? 1 : 0;
      cnt2 += s2;
    }
  };

  const bool stager = (tid < HID);
  float4 va = make_float4(0,0,0,0), vb = va;
  if (stager) {
    const float4* s0 = (const float4*)(W1 + tid * INDIM);
    va = s0[0]; vb = s0[1];
    double* dst = &wt[0][tid];
    dst[0*WTJ] = (double)va.x;  dst[1*WTJ] = (double)va.y;
    dst[2*WTJ] = (double)va.z;  dst[3*WTJ] = (double)va.w;
    dst[4*WTJ] = (double)vb.x;  dst[5*WTJ] = (double)vb.y;
    dst[6*WTJ] = (double)vb.z;  dst[7*WTJ] = (double)vb.w;
    const float4* s1 = (const float4*)(W1 + tid * INDIM + TD);
    va = s1[0]; vb = s1[1];
  }
  int cur = 0;
  int ld  = 2;
  __syncthreads();

  for (int tp = 0; tp < TSTEPS / 2; ++tp) {
    const uint2 ka = tf2x32(0u, 42u, 0u, (uint32_t)(2 * tp));
    const uint2 kb = tf2x32(0u, 42u, 0u, (uint32_t)(2 * tp + 1));
    const uint32_t kx[2] = { ka.x, kb.x };
    const uint32_t ky[2] = { ka.y, kb.y };

    const int cA = kh ? 7 : 0;
    const int cB = kh ? 13 : 7;
    for (int s = 0; s < 4; ++s) {
      const int q   = 4 * sg + s;
      const int row = g * 8 + (q & 7) + ((q >= 8) ? 8192 : 0);
      for (int c = cA; c < cB; ++c) {
        const int d = c * 64 + lane;
        const bool valid = (d < INDIM);
        float xv = 0.0f;
        if (valid) xv = x[row * INDIM + d];
        const uint32_t e = (uint32_t)row * (uint32_t)INDIM + (uint32_t)d;
#pragma unroll
        for (int tt = 0; tt < 2; ++tt) {
          int xb = 0;
          if (valid) {
            uint2 r = tf2x32(kx[tt], ky[tt], 0u, e);
            xb = xv > bits_to_unif(r.x ^ r.y);
          }
          unsigned long long m = __ballot(xb);
          if (lane == 0) {
            xib[tt][q][2*c]     = (uint32_t)m;
            xib[tt][q][2*c + 1] = (uint32_t)(m >> 32);
          }
        }
      }
    }
    __syncthreads();

#pragma unroll
    for (int s = 0; s < 4; ++s)
#pragma unroll
      for (int k = 0; k < 4; ++k) {
        mem1[s][k] = ((spv[s] >> k) & 1u) ? 0.0 : mem1[s][k] * 0.2;
        acc1[s][k] = 0.0;
      }

    for (int td = 0; td < NT; ++td) {
      if (stager) {
        double* dst = &wt[cur ^ 1][tid];
        dst[0*WTJ] = (double)va.x;  dst[1*WTJ] = (double)va.y;
        dst[2*WTJ] = (double)va.z;  dst[3*WTJ] = (double)va.w;
        dst[4*WTJ] = (double)vb.x;  dst[5*WTJ] = (double)vb.y;
        dst[6*WTJ] = (double)vb.z;  dst[7*WTJ] = (double)vb.w;
        const float4* src = (const float4*)(W1 + tid * INDIM + ld * TD);
        va = src[0]; vb = src[1];
      }
      ld = (ld + 1 == NT) ? 0 : ld + 1;

      const int wi = td >> 2, sh = (td & 3) * 8;
      uint32_t bA[4], bB[4];
#pragma unroll
      for (int s = 0; s < 4; ++s) {
        bA[s] = (uint32_t)__builtin_amdgcn_readfirstlane(
                  (int)((xib[0][4*sg + s][wi] >> sh) & 0xFFu));
        bB[s] = (uint32_t)__builtin_amdgcn_readfirstlane(
                  (int)((xib[1][4*sg + s][wi] >> sh) & 0xFFu));
      }

      const double* wp = &wt[cur][jb];
#pragma unroll
      for (int dt = 0; dt < TD; ++dt) {
        double wd[4];
#pragma unroll
        for (int k = 0; k < 4; ++k)
          wd[k] = wp[dt * WTJ + 64 * k];
#pragma unroll
        for (int s = 0; s < 4; ++s) {
          if (bA[s] & (1u << dt)) {
#pragma unroll
            for (int k = 0; k < 4; ++k) mem1[s][k] += wd[k];
          }
          if (bB[s] & (1u << dt)) {
#pragma unroll
            for (int k = 0; k < 4; ++k) acc1[s][k] += wd[k];
          }
        }
      }

      __syncthreads();
      cur ^= 1;
    }

#pragma unroll
    for (int s = 0; s < 4; ++s) {
      uint32_t m = 0u;
#pragma unroll
      for (int k = 0; k < 4; ++k) {
        mem1[s][k] += bb[k];
        if (mem1[s][k] > 0.5) m |= (1u << k);
      }
      spv[s] = m;
#pragma unroll
      for (int k = 0; k < 4; ++k) {
        unsigned long long bm = __ballot((m >> k) & 1u);
        const int w0 = 8 * kh + 2 * k;
        if (lane == 0 && w0 < SPW) {
          spk[0][4*sg + s][w0]     = (uint32_t)bm;
          spk[0][4*sg + s][w0 + 1] = (uint32_t)(bm >> 32);
        }
      }
    }

#pragma unroll
    for (int s = 0; s < 4; ++s) {
      uint32_t m = 0u;
#pragma unroll
      for (int k = 0; k < 4; ++k) {
        double v = ((spv[s] >> k) & 1u) ? 0.0 : mem1[s][k] * 0.2;
        v += acc1[s][k];
        v += bb[k];
        mem1[s][k] = v;
        if (v > 0.5) m |= (1u << k);
      }
      spv[s] = m;
#pragma unroll
      for (int k = 0; k < 4; ++k) {
        unsigned long long bm = __ballot((m >> k) & 1u);
        const int w0 = 8 * kh + 2 * k;
        if (lane == 0 && w0 < SPW) {
          spk[1][4*sg + s][w0]     = (uint32_t)bm;
          spk[1][4*sg + s][w0 + 1] = (uint32_t)(bm >> 32);
        }
      }
    }
    __syncthreads();

    layer2_step(0);
    layer2_step(1);
  }

  if (tid < 160) {
    const int row = g * 8 + (ls & 7) + ((ls >= 8) ? 8192 : 0);
    out[row * ODIM + lo] = (float)((double)cnt2 / 20.0);
  }
}

// ======================== launch ===========================================
extern "C" void kernel_launch(void* const* d_in, const int* in_sizes, int n_in,
                              void* d_out, int out_size, void* d_ws, size_t ws_size,
                              hipStream_t stream) {
  const float* x  = (const float*)d_in[0];
  const float* W1 = (const float*)d_in[1];
  const float* b1 = (const float*)d_in[2];
  const float* W2 = (const float*)d_in[3];
  const float* b2 = (const float*)d_in[4];
  // d_in[5] = time_window (int, ==20) — compile-time constant here.
  float* out = (float*)d_out;

  if (d_ws != nullptr && ws_size >= WS_NEED) {
    uint32_t* ws = (uint32_t*)d_ws;
    hipLaunchKernelGGL(snn_prep, dim3(4096 + 329), dim3(256), 0, stream,
                       x, W1, ws);
    hipLaunchKernelGGL(snn_l1, dim3(8 * NB_N * 8), dim3(256), 0, stream,
                       b1, ws);
    hipLaunchKernelGGL(snn_l2, dim3(640), dim3(256), 0, stream, W2, b2, ws, out);
  } else {
    hipLaunchKernelGGL(snn_fused_v6, dim3(1024), dim3(512), 0, stream,
                       x, W1, b1, W2, b2, out);
  }
}